// Round 9
// baseline (895.513 us; speedup 1.0000x reference)
//
#include <hip/hip_runtime.h>

#define N_NODES 16384
#define D_FEAT  128
#define HIDDEN  64
#define THRESH  0.85f
// |dot| band bracketing sqrt(0.85 +/- 0.004) (conservative supersets)
#define DLO     0.91978f
#define DHI     0.92413f
#define LQCAP   512
#define QMAX    450000
#define NBLK    1024         // 64 i-tiles x 16 j-chunks
#define JCH     1024         // j-chunk rows
#define NT      32           // 32-row j-tiles per chunk

typedef __attribute__((ext_vector_type(8))) short bf16x8;
typedef __attribute__((ext_vector_type(4))) float f32x4;

__device__ __forceinline__ unsigned short f32_to_bf16_rne(float f) {
    unsigned u = __float_as_uint(f);
    unsigned r = (u + 0x7FFFu + ((u >> 16) & 1u)) >> 16;
    return (unsigned short)r;
}

__device__ __forceinline__ void gl_lds16(const unsigned short* src, unsigned short* dst) {
    __builtin_amdgcn_global_load_lds(
        (const __attribute__((address_space(1))) unsigned int*)src,
        (__attribute__((address_space(3))) unsigned int*)dst, 16, 0, 0);
}

// ---------------------------------------------------------------------------
// Fused: bf16 hi/lo split of x + row sums s_i + zero acc/qcnt (blocks 0..2047)
// + W row sums (block 2048).
// ---------------------------------------------------------------------------
__global__ __launch_bounds__(256) void convert_rowsum_kernel(const float* __restrict__ x,
                                                             const float* __restrict__ W,
                                                             unsigned short* __restrict__ xhi,
                                                             unsigned short* __restrict__ xlo,
                                                             float* __restrict__ s,
                                                             float* __restrict__ wsum,
                                                             float* __restrict__ acc,
                                                             int* __restrict__ qcnt) {
    const int tid = threadIdx.x;
    if (blockIdx.x < 2048) {
        const int gidx = blockIdx.x * 256 + tid;         // float4 index
        float4 v = ((const float4*)x)[gidx];
        float f[4] = {v.x, v.y, v.z, v.w};
        ushort4 ho, lo;
        unsigned short* hp = &ho.x;
        unsigned short* lp = &lo.x;
        #pragma unroll
        for (int k = 0; k < 4; ++k) {
            unsigned short h = f32_to_bf16_rne(f[k]);
            float hf = __uint_as_float(((unsigned)h) << 16);
            hp[k] = h;
            lp[k] = f32_to_bf16_rne(f[k] - hf);
        }
        ((ushort4*)xhi)[gidx] = ho;
        ((ushort4*)xlo)[gidx] = lo;

        // 32-lane segmented reduce: one 128-float row per 32 threads
        float sum = (v.x + v.y) + (v.z + v.w);
        #pragma unroll
        for (int off = 16; off > 0; off >>= 1) sum += __shfl_xor(sum, off);
        if ((tid & 31) == 0) s[blockIdx.x * 8 + (tid >> 5)] = sum;

        if (tid < 8) acc[blockIdx.x * 8 + tid] = 0.0f;
        if (gidx == 0) *qcnt = 0;
    } else {
        // W rowsums: 64 rows x 128 = 2048 float4s, 8 passes
        #pragma unroll
        for (int p = 0; p < 8; ++p) {
            const int idx = p * 256 + tid;
            float4 v = ((const float4*)W)[idx];
            float sum = (v.x + v.y) + (v.z + v.w);
            #pragma unroll
            for (int off = 16; off > 0; off >>= 1) sum += __shfl_xor(sum, off);
            if ((tid & 31) == 0) wsum[p * 8 + (tid >> 5)] = sum;
        }
    }
}

// ---------------------------------------------------------------------------
// MFMA pairwise kernel. 1024 blocks = 64 i-tiles x 16 j-chunks -> 4 blocks/CU
// (16 waves/CU) for latency hiding.  2-buffer, 2-phase schedule:
// [vmcnt(0); barrier; stage t+1; compute t] — the vmcnt(0) drains loads
// issued one full compute phase earlier (free).  dot = hi*hi+hi*lo+lo*hi.
// Edge test in |d| space; band pairs -> exact f32 fixup.  Self-pair always
// counted (|d_ii| ~ 128 >= DHI); subtracted in out_kernel.
// ---------------------------------------------------------------------------
__global__ __launch_bounds__(256, 4) void pair_mfma(const unsigned short* __restrict__ xhi,
                                                    const unsigned short* __restrict__ xlo,
                                                    const float* __restrict__ s,
                                                    float* __restrict__ acc,
                                                    unsigned* __restrict__ gqueue,
                                                    int* __restrict__ gqcnt) {
    __shared__ unsigned short Bs[2][2][32][128];   // 32 KB: [buf][plane][row][col]
    __shared__ float s_lds[JCH];                   // 4 KB
    __shared__ unsigned lq[LQCAP];
    __shared__ int lqcnt, lqbase;

    const int tid  = threadIdx.x;
    const int lane = tid & 63;
    const int w    = tid >> 6;
    const int l15  = lane & 15, l4 = lane >> 4, l7 = lane & 7;

    // XCD-aware bijective swizzle: XCD k (bid%8) owns j-chunks 2k,2k+1.
    const int bid = blockIdx.x;
    const int swz = (bid & 7) * 128 + (bid >> 3);
    const int it  = swz & 63;                 // i-tile (256 rows)
    const int jc  = swz >> 6;                 // j-chunk (1024 rows), 0..15
    const int i0  = it * 256 + w * 64;        // this wave's 64 rows
    const int jb0 = jc * JCH;

    // ---- persistent A fragments: 4 row-frags x 4 k-chunks x {hi,lo} ----
    bf16x8 ahi[4][4], alo[4][4];
    {
        const int abase = (i0 + l15) * D_FEAT + l4 * 8;
        #pragma unroll
        for (int rf = 0; rf < 4; ++rf)
            #pragma unroll
            for (int kc = 0; kc < 4; ++kc) {
                const int off = abase + rf * 16 * D_FEAT + kc * 32;
                ahi[rf][kc] = *(const bf16x8*)(xhi + off);
                alo[rf][kc] = *(const bf16x8*)(xlo + off);
            }
    }

    // ---- stage s chunk (1024 floats = 1 float4/thread), zero lqcnt ----
    ((float4*)s_lds)[tid] = ((const float4*)(s + jb0))[tid];
    if (tid == 0) lqcnt = 0;
    __syncthreads();   // full drain once, BEFORE staging issues

    // Staging: 16 KB/tile = 16 x 1KB gl_lds; wave w issues ids w*4..+3.
    // id<8 -> hi plane rows (id&7)*4..+3 ; id>=8 -> lo plane.
    // Source granule XOR-pre-swizzled by (row&7); LDS dest linear (G21).
    int src_off[4]; int dst_off[4]; int plane_sel[4];
    #pragma unroll
    for (int q = 0; q < 4; ++q) {
        const int id = w * 4 + q;
        const int rowt = (id & 7) * 4 + l4;
        plane_sel[q] = id >> 3;
        src_off[q] = rowt * D_FEAT + ((l15 ^ (rowt & 7)) * 8);
        dst_off[q] = (id >> 3) * 4096 + (id & 7) * 512;   // elements
    }
    unsigned short* const BsE = &Bs[0][0][0][0];

    // ---- prologue: stage tile 0 into buf0 (4 loads/wave outstanding) ----
    {
        const int jelem = jb0 * D_FEAT;
        #pragma unroll
        for (int q = 0; q < 4; ++q) {
            const unsigned short* sp = (plane_sel[q] ? xlo : xhi) + jelem + src_off[q];
            gl_lds16(sp, BsE + dst_off[q]);
        }
    }

    float accf[4][4] = {{0.f}};
    const char* const BsBytes = (const char*)BsE;
    const int rbyte = l15 * 256;
    int swzb[4];
    #pragma unroll
    for (int kc = 0; kc < 4; ++kc) swzb[kc] = (((kc * 4 + l4) ^ l7) * 16);

    int buf = 0;
    for (int t = 0; t < NT; ++t) {
        // tile t's loads were issued one full compute phase ago -> cheap drain
        asm volatile("s_waitcnt vmcnt(0)" ::: "memory");
        __builtin_amdgcn_s_barrier();

        // stage tile t+1 into buf^1 (overlaps compute below)
        if (t < NT - 1) {
            const int jelem = (jb0 + (t + 1) * 32) * D_FEAT;
            unsigned short* db = BsE + (buf ^ 1) * 8192;
            #pragma unroll
            for (int q = 0; q < 4; ++q) {
                const unsigned short* sp = (plane_sel[q] ? xlo : xhi) + jelem + src_off[q];
                gl_lds16(sp, db + dst_off[q]);
            }
        }

        const int jb = jb0 + t * 32;
        const char* bp = BsBytes + buf * 16384;

        #pragma unroll
        for (int cg = 0; cg < 2; ++cg) {
            f32x4 C[4];
            #pragma unroll
            for (int rf = 0; rf < 4; ++rf) C[rf] = (f32x4){0.f, 0.f, 0.f, 0.f};

            __builtin_amdgcn_s_setprio(1);
            #pragma unroll
            for (int kc = 0; kc < 4; ++kc) {
                const bf16x8 bh = *(const bf16x8*)(bp + cg * 4096 + rbyte + swzb[kc]);
                const bf16x8 bl = *(const bf16x8*)(bp + 8192 + cg * 4096 + rbyte + swzb[kc]);
                #pragma unroll
                for (int rf = 0; rf < 4; ++rf) {
                    C[rf] = __builtin_amdgcn_mfma_f32_16x16x32_bf16(ahi[rf][kc], bh, C[rf], 0, 0, 0);
                    C[rf] = __builtin_amdgcn_mfma_f32_16x16x32_bf16(alo[rf][kc], bh, C[rf], 0, 0, 0);
                    C[rf] = __builtin_amdgcn_mfma_f32_16x16x32_bf16(ahi[rf][kc], bl, C[rf], 0, 0, 0);
                }
            }
            __builtin_amdgcn_s_setprio(0);

            const int jcol = jb + cg * 16 + l15;
            const float svc = s_lds[t * 32 + cg * 16 + l15];   // broadcast, free
            bool anyband = false;
            #pragma unroll
            for (int rf = 0; rf < 4; ++rf)
                #pragma unroll
                for (int r = 0; r < 4; ++r) {
                    const float ad = fabsf(C[rf][r]);
                    accf[rf][r] += (ad >= DHI) ? svc : 0.f;
                    anyband = anyband || (ad >= DLO && ad < DHI);
                }
            // ONE wave-uniform branch per cg; rare recompute-and-enqueue
            if (__any(anyband)) {
                #pragma unroll
                for (int rf = 0; rf < 4; ++rf)
                    #pragma unroll
                    for (int r = 0; r < 4; ++r) {
                        const float ad = fabsf(C[rf][r]);
                        if (ad >= DLO && ad < DHI) {
                            int p = atomicAdd(&lqcnt, 1);
                            if (p < LQCAP)
                                lq[p] = (((unsigned)(i0 + rf * 16 + l4 * 4 + r)) << 14) | (unsigned)jcol;
                        }
                    }
            }
        }
        buf ^= 1;
    }

    __syncthreads();   // post-loop: full drain OK (once)

    // ---- flush band queue ----
    if (tid == 0) {
        int c = lqcnt; if (c > LQCAP) c = LQCAP;
        lqbase = atomicAdd(gqcnt, c);
        lqcnt = c;
    }
    __syncthreads();
    for (int p = tid; p < lqcnt; p += 256) gqueue[lqbase + p] = lq[p];

    // ---- reduce accf across the 16 lanes of each row-group, atomicAdd ----
    #pragma unroll
    for (int rf = 0; rf < 4; ++rf)
        #pragma unroll
        for (int r = 0; r < 4; ++r) {
            float v = accf[rf][r];
            v += __shfl_xor(v, 1);
            v += __shfl_xor(v, 2);
            v += __shfl_xor(v, 4);
            v += __shfl_xor(v, 8);
            if (l15 == 0) atomicAdd(&acc[i0 + rf * 16 + l4 * 4 + r], v);
        }
}

// ---------------------------------------------------------------------------
// Exact f32 re-decision for band pairs: one pair per wave.
// ---------------------------------------------------------------------------
__global__ __launch_bounds__(256) void fixup_kernel(const unsigned* __restrict__ q,
                                                    const int* __restrict__ qcnt,
                                                    const float* __restrict__ x,
                                                    const float* __restrict__ s,
                                                    float* __restrict__ acc) {
    int n = *qcnt; if (n > QMAX) n = QMAX;
    const int gw = (blockIdx.x * 256 + threadIdx.x) >> 6;
    const int lane = threadIdx.x & 63;
    const int nw = (gridDim.x * 256) >> 6;
    for (int p = gw; p < n; p += nw) {
        const unsigned e = q[p];
        const int i = (int)(e >> 14), j = (int)(e & 16383u);
        const float2 av = ((const float2*)(x + (size_t)i * D_FEAT))[lane];
        const float2 bv = ((const float2*)(x + (size_t)j * D_FEAT))[lane];
        float d = fmaf(av.y, bv.y, av.x * bv.x);
        #pragma unroll
        for (int off = 32; off > 0; off >>= 1) d += __shfl_xor(d, off);
        if (lane == 0) {
            const float tt = fmaf(d, d, -THRESH);
            if (tt >= 0.f) atomicAdd(&acc[i], s[j]);
        }
    }
}

// ---------------------------------------------------------------------------
// out[i][h] = ((acc[i] - s[i])/128) * wsum[h] + b[h]
// ---------------------------------------------------------------------------
__global__ __launch_bounds__(256) void out_kernel(const float* __restrict__ acc,
                                                  const float* __restrict__ s,
                                                  const float* __restrict__ wsum,
                                                  const float* __restrict__ b,
                                                  float* __restrict__ out) {
    int gid = blockIdx.x * blockDim.x + threadIdx.x;
    int i = gid >> 6;
    int h = gid & 63;
    float a = (acc[i] - s[i]) * (1.0f / 128.0f);
    out[gid] = fmaf(a, wsum[h], b[h]);
}

// ---------------------------------------------------------------------------
extern "C" void kernel_launch(void* const* d_in, const int* in_sizes, int n_in,
                              void* d_out, int out_size, void* d_ws, size_t ws_size,
                              hipStream_t stream) {
    const float* x = (const float*)d_in[0];   // [16384,128]
    const float* W = (const float*)d_in[1];   // [64,128]
    const float* b = (const float*)d_in[2];   // [64]
    float* out = (float*)d_out;               // [16384,64]

    float*    s     = (float*)d_ws;                            // 64 KB
    float*    acc   = (float*)((char*)d_ws + 65536);           // 64 KB
    float*    wsum  = (float*)((char*)d_ws + 131072);          // 256 B
    int*      qcnt  = (int*)((char*)d_ws + 131328);
    unsigned* queue = (unsigned*)((char*)d_ws + 262144);       // ~1.8 MB
    unsigned short* xhi = (unsigned short*)((char*)d_ws + (2u << 20));
    unsigned short* xlo = (unsigned short*)((char*)d_ws + (6u << 20));

    convert_rowsum_kernel<<<dim3(2049), dim3(256), 0, stream>>>(x, W, xhi, xlo, s, wsum, acc, qcnt);
    pair_mfma<<<dim3(NBLK), dim3(256), 0, stream>>>(xhi, xlo, s, acc, queue, qcnt);
    fixup_kernel<<<dim3(256), dim3(256), 0, stream>>>(queue, qcnt, x, s, acc);
    out_kernel<<<dim3(N_NODES * HIDDEN / 256), dim3(256), 0, stream>>>(acc, s, wsum, b, out);
}

// Round 10
// 733.971 us; speedup vs baseline: 1.2201x; 1.2201x over previous
//
#include <hip/hip_runtime.h>

#define N_NODES 16384
#define D_FEAT  128
#define HIDDEN  64
#define THRESH  0.85f
// |dot| band bracketing sqrt(0.85 +/- 0.004) (conservative supersets)
#define DLO     0.91978f
#define DHI     0.92413f
#define LQCAP   512
#define QMAX    450000
#define NBLK    1024         // 64 i-tiles x 16 j-chunks
#define JCH     1024         // j-chunk rows
#define NT      32           // 32-row j-tiles per chunk

typedef __attribute__((ext_vector_type(8))) short bf16x8;
typedef __attribute__((ext_vector_type(4))) float f32x4;

__device__ __forceinline__ unsigned short f32_to_bf16_rne(float f) {
    unsigned u = __float_as_uint(f);
    unsigned r = (u + 0x7FFFu + ((u >> 16) & 1u)) >> 16;
    return (unsigned short)r;
}

__device__ __forceinline__ void gl_lds16(const unsigned short* src, unsigned short* dst) {
    __builtin_amdgcn_global_load_lds(
        (const __attribute__((address_space(1))) unsigned int*)src,
        (__attribute__((address_space(3))) unsigned int*)dst, 16, 0, 0);
}

// ---------------------------------------------------------------------------
// Fused: bf16 hi/lo split of x + row sums s_i + zero acc/qcnt (blocks 0..2047)
// + W row sums (block 2048).
// ---------------------------------------------------------------------------
__global__ __launch_bounds__(256) void convert_rowsum_kernel(const float* __restrict__ x,
                                                             const float* __restrict__ W,
                                                             unsigned short* __restrict__ xhi,
                                                             unsigned short* __restrict__ xlo,
                                                             float* __restrict__ s,
                                                             float* __restrict__ wsum,
                                                             float* __restrict__ acc,
                                                             int* __restrict__ qcnt) {
    const int tid = threadIdx.x;
    if (blockIdx.x < 2048) {
        const int gidx = blockIdx.x * 256 + tid;         // float4 index
        float4 v = ((const float4*)x)[gidx];
        float f[4] = {v.x, v.y, v.z, v.w};
        ushort4 ho, lo;
        unsigned short* hp = &ho.x;
        unsigned short* lp = &lo.x;
        #pragma unroll
        for (int k = 0; k < 4; ++k) {
            unsigned short h = f32_to_bf16_rne(f[k]);
            float hf = __uint_as_float(((unsigned)h) << 16);
            hp[k] = h;
            lp[k] = f32_to_bf16_rne(f[k] - hf);
        }
        ((ushort4*)xhi)[gidx] = ho;
        ((ushort4*)xlo)[gidx] = lo;

        // 32-lane segmented reduce: one 128-float row per 32 threads
        float sum = (v.x + v.y) + (v.z + v.w);
        #pragma unroll
        for (int off = 16; off > 0; off >>= 1) sum += __shfl_xor(sum, off);
        if ((tid & 31) == 0) s[blockIdx.x * 8 + (tid >> 5)] = sum;

        if (tid < 8) acc[blockIdx.x * 8 + tid] = 0.0f;
        if (gidx == 0) *qcnt = 0;
    } else {
        // W rowsums: 64 rows x 128 = 2048 float4s, 8 passes
        #pragma unroll
        for (int p = 0; p < 8; ++p) {
            const int idx = p * 256 + tid;
            float4 v = ((const float4*)W)[idx];
            float sum = (v.x + v.y) + (v.z + v.w);
            #pragma unroll
            for (int off = 16; off > 0; off >>= 1) sum += __shfl_xor(sum, off);
            if ((tid & 31) == 0) wsum[p * 8 + (tid >> 5)] = sum;
        }
    }
}

// ---------------------------------------------------------------------------
// MFMA pairwise kernel. 1024 blocks = 64 i-tiles x 16 j-chunks.
// __launch_bounds__(256,3): 3 waves/EU -> VGPR cap ~170 >= ~112 demand (NO
// spill — round-9's (256,4) capped at 128 unified and spilled to scratch),
// 3 blocks/CU = 12 waves/CU for latency hiding.  2-buffer 2-phase schedule:
// [vmcnt(0); barrier; stage t+1; compute t] — drain covers loads issued one
// full compute phase earlier; other resident blocks cover the drain.
// dot = hi*hi+hi*lo+lo*hi.  Edge test in |d| space; band -> exact fixup.
// Self-pair always counted (|d_ii| ~ 128 >= DHI); subtracted in out_kernel.
// ---------------------------------------------------------------------------
__global__ __launch_bounds__(256, 3) void pair_mfma(const unsigned short* __restrict__ xhi,
                                                    const unsigned short* __restrict__ xlo,
                                                    const float* __restrict__ s,
                                                    float* __restrict__ acc,
                                                    unsigned* __restrict__ gqueue,
                                                    int* __restrict__ gqcnt) {
    __shared__ unsigned short Bs[2][2][32][128];   // 32 KB: [buf][plane][row][col]
    __shared__ float s_lds[JCH];                   // 4 KB
    __shared__ unsigned lq[LQCAP];
    __shared__ int lqcnt, lqbase;

    const int tid  = threadIdx.x;
    const int lane = tid & 63;
    const int w    = tid >> 6;
    const int l15  = lane & 15, l4 = lane >> 4, l7 = lane & 7;

    // XCD-aware bijective swizzle: XCD k (bid%8) owns j-chunks 2k,2k+1.
    const int bid = blockIdx.x;
    const int swz = (bid & 7) * 128 + (bid >> 3);
    const int it  = swz & 63;                 // i-tile (256 rows)
    const int jc  = swz >> 6;                 // j-chunk (1024 rows), 0..15
    const int i0  = it * 256 + w * 64;        // this wave's 64 rows
    const int jb0 = jc * JCH;

    // ---- persistent A fragments: 4 row-frags x 4 k-chunks x {hi,lo} ----
    bf16x8 ahi[4][4], alo[4][4];
    {
        const int abase = (i0 + l15) * D_FEAT + l4 * 8;
        #pragma unroll
        for (int rf = 0; rf < 4; ++rf)
            #pragma unroll
            for (int kc = 0; kc < 4; ++kc) {
                const int off = abase + rf * 16 * D_FEAT + kc * 32;
                ahi[rf][kc] = *(const bf16x8*)(xhi + off);
                alo[rf][kc] = *(const bf16x8*)(xlo + off);
            }
    }

    // ---- stage s chunk (1024 floats = 1 float4/thread), zero lqcnt ----
    ((float4*)s_lds)[tid] = ((const float4*)(s + jb0))[tid];
    if (tid == 0) lqcnt = 0;
    __syncthreads();   // full drain once, BEFORE staging issues

    // Staging: 16 KB/tile = 16 x 1KB gl_lds; wave w issues ids w*4..+3.
    // id<8 -> hi plane rows (id&7)*4..+3 ; id>=8 -> lo plane.
    // Source granule XOR-pre-swizzled by (row&7); LDS dest linear (G21).
    int src_off[4]; int dst_off[4]; int plane_sel[4];
    #pragma unroll
    for (int q = 0; q < 4; ++q) {
        const int id = w * 4 + q;
        const int rowt = (id & 7) * 4 + l4;
        plane_sel[q] = id >> 3;
        src_off[q] = rowt * D_FEAT + ((l15 ^ (rowt & 7)) * 8);
        dst_off[q] = (id >> 3) * 4096 + (id & 7) * 512;   // elements
    }
    unsigned short* const BsE = &Bs[0][0][0][0];

    // ---- prologue: stage tile 0 into buf0 (4 loads/wave outstanding) ----
    {
        const int jelem = jb0 * D_FEAT;
        #pragma unroll
        for (int q = 0; q < 4; ++q) {
            const unsigned short* sp = (plane_sel[q] ? xlo : xhi) + jelem + src_off[q];
            gl_lds16(sp, BsE + dst_off[q]);
        }
    }

    float accf[4][4] = {{0.f}};
    const char* const BsBytes = (const char*)BsE;
    const int rbyte = l15 * 256;
    int swzb[4];
    #pragma unroll
    for (int kc = 0; kc < 4; ++kc) swzb[kc] = (((kc * 4 + l4) ^ l7) * 16);

    int buf = 0;
    for (int t = 0; t < NT; ++t) {
        // tile t's loads were issued one full compute phase ago -> cheap drain
        asm volatile("s_waitcnt vmcnt(0)" ::: "memory");
        __builtin_amdgcn_s_barrier();

        // stage tile t+1 into buf^1 (overlaps compute below)
        if (t < NT - 1) {
            const int jelem = (jb0 + (t + 1) * 32) * D_FEAT;
            unsigned short* db = BsE + (buf ^ 1) * 8192;
            #pragma unroll
            for (int q = 0; q < 4; ++q) {
                const unsigned short* sp = (plane_sel[q] ? xlo : xhi) + jelem + src_off[q];
                gl_lds16(sp, db + dst_off[q]);
            }
        }

        const int jb = jb0 + t * 32;
        const char* bp = BsBytes + buf * 16384;

        #pragma unroll
        for (int cg = 0; cg < 2; ++cg) {
            f32x4 C[4];
            #pragma unroll
            for (int rf = 0; rf < 4; ++rf) C[rf] = (f32x4){0.f, 0.f, 0.f, 0.f};

            __builtin_amdgcn_s_setprio(1);
            #pragma unroll
            for (int kc = 0; kc < 4; ++kc) {
                const bf16x8 bh = *(const bf16x8*)(bp + cg * 4096 + rbyte + swzb[kc]);
                const bf16x8 bl = *(const bf16x8*)(bp + 8192 + cg * 4096 + rbyte + swzb[kc]);
                #pragma unroll
                for (int rf = 0; rf < 4; ++rf) {
                    C[rf] = __builtin_amdgcn_mfma_f32_16x16x32_bf16(ahi[rf][kc], bh, C[rf], 0, 0, 0);
                    C[rf] = __builtin_amdgcn_mfma_f32_16x16x32_bf16(alo[rf][kc], bh, C[rf], 0, 0, 0);
                    C[rf] = __builtin_amdgcn_mfma_f32_16x16x32_bf16(ahi[rf][kc], bl, C[rf], 0, 0, 0);
                }
            }
            __builtin_amdgcn_s_setprio(0);

            const int jcol = jb + cg * 16 + l15;
            const float svc = s_lds[t * 32 + cg * 16 + l15];   // broadcast, free
            bool anyband = false;
            #pragma unroll
            for (int rf = 0; rf < 4; ++rf)
                #pragma unroll
                for (int r = 0; r < 4; ++r) {
                    const float ad = fabsf(C[rf][r]);
                    accf[rf][r] += (ad >= DHI) ? svc : 0.f;
                    anyband = anyband || (ad >= DLO && ad < DHI);
                }
            // ONE wave-uniform branch per cg; rare recompute-and-enqueue
            if (__any(anyband)) {
                #pragma unroll
                for (int rf = 0; rf < 4; ++rf)
                    #pragma unroll
                    for (int r = 0; r < 4; ++r) {
                        const float ad = fabsf(C[rf][r]);
                        if (ad >= DLO && ad < DHI) {
                            int p = atomicAdd(&lqcnt, 1);
                            if (p < LQCAP)
                                lq[p] = (((unsigned)(i0 + rf * 16 + l4 * 4 + r)) << 14) | (unsigned)jcol;
                        }
                    }
            }
        }
        buf ^= 1;
    }

    __syncthreads();   // post-loop: full drain OK (once)

    // ---- flush band queue ----
    if (tid == 0) {
        int c = lqcnt; if (c > LQCAP) c = LQCAP;
        lqbase = atomicAdd(gqcnt, c);
        lqcnt = c;
    }
    __syncthreads();
    for (int p = tid; p < lqcnt; p += 256)
        if (lqbase + p < QMAX) gqueue[lqbase + p] = lq[p];

    // ---- reduce accf across the 16 lanes of each row-group, atomicAdd ----
    #pragma unroll
    for (int rf = 0; rf < 4; ++rf)
        #pragma unroll
        for (int r = 0; r < 4; ++r) {
            float v = accf[rf][r];
            v += __shfl_xor(v, 1);
            v += __shfl_xor(v, 2);
            v += __shfl_xor(v, 4);
            v += __shfl_xor(v, 8);
            if (l15 == 0) atomicAdd(&acc[i0 + rf * 16 + l4 * 4 + r], v);
        }
}

// ---------------------------------------------------------------------------
// Exact f32 re-decision for band pairs: one pair per wave.
// ---------------------------------------------------------------------------
__global__ __launch_bounds__(256) void fixup_kernel(const unsigned* __restrict__ q,
                                                    const int* __restrict__ qcnt,
                                                    const float* __restrict__ x,
                                                    const float* __restrict__ s,
                                                    float* __restrict__ acc) {
    int n = *qcnt; if (n > QMAX) n = QMAX;
    const int gw = (blockIdx.x * 256 + threadIdx.x) >> 6;
    const int lane = threadIdx.x & 63;
    const int nw = (gridDim.x * 256) >> 6;
    for (int p = gw; p < n; p += nw) {
        const unsigned e = q[p];
        const int i = (int)(e >> 14), j = (int)(e & 16383u);
        const float2 av = ((const float2*)(x + (size_t)i * D_FEAT))[lane];
        const float2 bv = ((const float2*)(x + (size_t)j * D_FEAT))[lane];
        float d = fmaf(av.y, bv.y, av.x * bv.x);
        #pragma unroll
        for (int off = 32; off > 0; off >>= 1) d += __shfl_xor(d, off);
        if (lane == 0) {
            const float tt = fmaf(d, d, -THRESH);
            if (tt >= 0.f) atomicAdd(&acc[i], s[j]);
        }
    }
}

// ---------------------------------------------------------------------------
// out[i][h] = ((acc[i] - s[i])/128) * wsum[h] + b[h]
// ---------------------------------------------------------------------------
__global__ __launch_bounds__(256) void out_kernel(const float* __restrict__ acc,
                                                  const float* __restrict__ s,
                                                  const float* __restrict__ wsum,
                                                  const float* __restrict__ b,
                                                  float* __restrict__ out) {
    int gid = blockIdx.x * blockDim.x + threadIdx.x;
    int i = gid >> 6;
    int h = gid & 63;
    float a = (acc[i] - s[i]) * (1.0f / 128.0f);
    out[gid] = fmaf(a, wsum[h], b[h]);
}

// ---------------------------------------------------------------------------
extern "C" void kernel_launch(void* const* d_in, const int* in_sizes, int n_in,
                              void* d_out, int out_size, void* d_ws, size_t ws_size,
                              hipStream_t stream) {
    const float* x = (const float*)d_in[0];   // [16384,128]
    const float* W = (const float*)d_in[1];   // [64,128]
    const float* b = (const float*)d_in[2];   // [64]
    float* out = (float*)d_out;               // [16384,64]

    float*    s     = (float*)d_ws;                            // 64 KB
    float*    acc   = (float*)((char*)d_ws + 65536);           // 64 KB
    float*    wsum  = (float*)((char*)d_ws + 131072);          // 256 B
    int*      qcnt  = (int*)((char*)d_ws + 131328);
    unsigned* queue = (unsigned*)((char*)d_ws + 262144);       // ~1.8 MB
    unsigned short* xhi = (unsigned short*)((char*)d_ws + (2u << 20));
    unsigned short* xlo = (unsigned short*)((char*)d_ws + (6u << 20));

    convert_rowsum_kernel<<<dim3(2049), dim3(256), 0, stream>>>(x, W, xhi, xlo, s, wsum, acc, qcnt);
    pair_mfma<<<dim3(NBLK), dim3(256), 0, stream>>>(xhi, xlo, s, acc, queue, qcnt);
    fixup_kernel<<<dim3(256), dim3(256), 0, stream>>>(queue, qcnt, x, s, acc);
    out_kernel<<<dim3(N_NODES * HIDDEN / 256), dim3(256), 0, stream>>>(acc, s, wsum, b, out);
}

// Round 13
// 327.802 us; speedup vs baseline: 2.7319x; 2.2391x over previous
//
#include <hip/hip_runtime.h>

#define N_NODES 16384
#define D_FEAT  128
#define HIDDEN  64
#define THRESH  0.85f
// |dot| band bracketing sqrt(0.85 +/- 0.004) (conservative supersets)
#define DLO     0.91978f
#define DHI     0.92413f
#define LQCAP   512
#define QMAX    450000
#define NT      8            // 32-row j-tiles per 256-row j-chunk

typedef __attribute__((ext_vector_type(8))) short bf16x8;
typedef __attribute__((ext_vector_type(4))) float f32x4;

__device__ __forceinline__ unsigned short f32_to_bf16_rne(float f) {
    unsigned u = __float_as_uint(f);
    unsigned r = (u + 0x7FFFu + ((u >> 16) & 1u)) >> 16;
    return (unsigned short)r;
}

__device__ __forceinline__ void gl_lds16(const unsigned short* src, unsigned short* dst) {
    __builtin_amdgcn_global_load_lds(
        (const __attribute__((address_space(1))) unsigned int*)src,
        (__attribute__((address_space(3))) unsigned int*)dst, 16, 0, 0);
}

// ---------------------------------------------------------------------------
// Fused: bf16 hi/lo split of x + row sums s_i + zero acc/qcnt (blocks 0..2047)
// + W row sums (block 2048).
// ---------------------------------------------------------------------------
__global__ __launch_bounds__(256) void convert_rowsum_kernel(const float* __restrict__ x,
                                                             const float* __restrict__ W,
                                                             unsigned short* __restrict__ xhi,
                                                             unsigned short* __restrict__ xlo,
                                                             float* __restrict__ s,
                                                             float* __restrict__ wsum,
                                                             float* __restrict__ acc,
                                                             int* __restrict__ qcnt) {
    const int tid = threadIdx.x;
    if (blockIdx.x < 2048) {
        const int gidx = blockIdx.x * 256 + tid;         // float4 index
        float4 v = ((const float4*)x)[gidx];
        float f[4] = {v.x, v.y, v.z, v.w};
        ushort4 ho, lo;
        unsigned short* hp = &ho.x;
        unsigned short* lp = &lo.x;
        #pragma unroll
        for (int k = 0; k < 4; ++k) {
            unsigned short h = f32_to_bf16_rne(f[k]);
            float hf = __uint_as_float(((unsigned)h) << 16);
            hp[k] = h;
            lp[k] = f32_to_bf16_rne(f[k] - hf);
        }
        ((ushort4*)xhi)[gidx] = ho;
        ((ushort4*)xlo)[gidx] = lo;

        // 32-lane segmented reduce: one 128-float row per 32 threads
        float sum = (v.x + v.y) + (v.z + v.w);
        #pragma unroll
        for (int off = 16; off > 0; off >>= 1) sum += __shfl_xor(sum, off);
        if ((tid & 31) == 0) s[blockIdx.x * 8 + (tid >> 5)] = sum;

        if (tid < 8) acc[blockIdx.x * 8 + tid] = 0.0f;
        if (gidx == 0) *qcnt = 0;
    } else {
        // W rowsums: 64 rows x 128 = 2048 float4s, 8 passes
        #pragma unroll
        for (int p = 0; p < 8; ++p) {
            const int idx = p * 256 + tid;
            float4 v = ((const float4*)W)[idx];
            float sum = (v.x + v.y) + (v.z + v.w);
            #pragma unroll
            for (int off = 16; off > 0; off >>= 1) sum += __shfl_xor(sum, off);
            if ((tid & 31) == 0) wsum[p * 8 + (tid >> 5)] = sum;
        }
    }
}

// ---------------------------------------------------------------------------
// Triangular MFMA pairwise kernel: grid (jc=64, it=64), early-exit jc<it.
// Each block: 256 i-rows x 256 j-rows, NT=8 j-tiles of 32.  Forward acc
// (acc[i]+=s[j]) for every block; transpose acc (acc[j]+=s[i]) only off-diag
// via per-wave jacc slab (each col written once per wave -> no atomics).
// Round-8-verified 3-buffer schedule: vmcnt(4) + raw s_barrier, setprio.
// dot = hi*hi+hi*lo+lo*hi; |d|-band pairs -> exact fixup (sym flag bit31).
// Self-pair always counted; subtracted in out_kernel.
// ---------------------------------------------------------------------------
__global__ __launch_bounds__(256, 2) void pair_mfma(const unsigned short* __restrict__ xhi,
                                                    const unsigned short* __restrict__ xlo,
                                                    const float* __restrict__ s,
                                                    float* __restrict__ acc,
                                                    unsigned* __restrict__ gqueue,
                                                    int* __restrict__ gqcnt) {
    const int jcB = blockIdx.x;    // j-chunk 0..63
    const int itB = blockIdx.y;    // i-tile  0..63
    if (jcB < itB) return;         // triangle only (uniform exit, no barriers yet)
    const bool offdiag = (jcB != itB);

    __shared__ unsigned short Bs[3][2][32][128];   // 48 KB
    __shared__ float s_lds[256];                   // j-chunk row sums
    __shared__ float si_lds[256];                  // i-tile row sums
    __shared__ float jacc[4][256];                 // per-wave transpose acc
    __shared__ unsigned lq[LQCAP];
    __shared__ int lqcnt, lqbase;

    const int tid  = threadIdx.x;
    const int lane = tid & 63;
    const int w    = tid >> 6;
    const int l15  = lane & 15, l4 = lane >> 4, l7 = lane & 7;

    const int i0  = itB * 256 + w * 64;       // this wave's 64 i-rows
    const int jb0 = jcB * 256;

    // ---- persistent A fragments: 4 row-frags x 4 k-chunks x {hi,lo} ----
    bf16x8 ahi[4][4], alo[4][4];
    {
        const int abase = (i0 + l15) * D_FEAT + l4 * 8;
        #pragma unroll
        for (int rf = 0; rf < 4; ++rf)
            #pragma unroll
            for (int kc = 0; kc < 4; ++kc) {
                const int off = abase + rf * 16 * D_FEAT + kc * 32;
                ahi[rf][kc] = *(const bf16x8*)(xhi + off);
                alo[rf][kc] = *(const bf16x8*)(xlo + off);
            }
    }

    // ---- stage row-sum slabs, zero lqcnt ----
    s_lds[tid]  = s[jb0 + tid];
    si_lds[tid] = s[itB * 256 + tid];
    if (tid == 0) lqcnt = 0;
    __syncthreads();   // full drain once, BEFORE gl_lds staging issues

    // Staging: 16 KB/tile = 16 x 1KB gl_lds; wave w issues ids w*4..+3.
    // id<8 -> hi plane rows (id&7)*4..+3 ; id>=8 -> lo plane.
    // Source granule XOR-pre-swizzled by (row&7); LDS dest linear (G21).
    int src_off[4]; int dst_off[4]; int plane_sel[4];
    #pragma unroll
    for (int q = 0; q < 4; ++q) {
        const int id = w * 4 + q;
        const int rowt = (id & 7) * 4 + l4;
        plane_sel[q] = id >> 3;
        src_off[q] = rowt * D_FEAT + ((l15 ^ (rowt & 7)) * 8);
        dst_off[q] = (id >> 3) * 4096 + (id & 7) * 512;   // elements
    }
    unsigned short* const BsE = &Bs[0][0][0][0];

    // ---- prologue: stage tiles 0,1 into buffers 0,1 (8 outstanding/wave) ----
    #pragma unroll
    for (int tt = 0; tt < 2; ++tt) {
        const int jelem = (jb0 + tt * 32) * D_FEAT;
        #pragma unroll
        for (int q = 0; q < 4; ++q) {
            const unsigned short* sp = (plane_sel[q] ? xlo : xhi) + jelem + src_off[q];
            gl_lds16(sp, BsE + tt * 8192 + dst_off[q]);
        }
    }

    float accf[4][4] = {{0.f}};
    const char* const BsBytes = (const char*)BsE;
    const int rbyte = l15 * 256;
    int swzb[4];
    #pragma unroll
    for (int kc = 0; kc < 4; ++kc) swzb[kc] = (((kc * 4 + l4) ^ l7) * 16);

    const unsigned symflag = offdiag ? 0x80000000u : 0u;
    int bufc = 0, bufs = 2;    // compute buf = t%3, stage buf = (t+2)%3
    for (int t = 0; t < NT; ++t) {
        // T4: counted wait — tile t landed; later tiles stay in flight
        asm volatile("s_waitcnt vmcnt(4)" ::: "memory");
        __builtin_amdgcn_s_barrier();

        // stage tile (t+2)&7 (dead-but-in-bounds on last 2 iters)
        {
            const int jelem = (jb0 + ((t + 2) & 7) * 32) * D_FEAT;
            unsigned short* db = BsE + bufs * 8192;
            #pragma unroll
            for (int q = 0; q < 4; ++q) {
                const unsigned short* sp = (plane_sel[q] ? xlo : xhi) + jelem + src_off[q];
                gl_lds16(sp, db + dst_off[q]);
            }
        }

        const int jb = jb0 + t * 32;
        const char* bp = BsBytes + bufc * 16384;

        #pragma unroll
        for (int cg = 0; cg < 2; ++cg) {
            f32x4 C[4];
            #pragma unroll
            for (int rf = 0; rf < 4; ++rf) C[rf] = (f32x4){0.f, 0.f, 0.f, 0.f};

            __builtin_amdgcn_s_setprio(1);
            #pragma unroll
            for (int kc = 0; kc < 4; ++kc) {
                const bf16x8 bh = *(const bf16x8*)(bp + cg * 4096 + rbyte + swzb[kc]);
                const bf16x8 bl = *(const bf16x8*)(bp + 8192 + cg * 4096 + rbyte + swzb[kc]);
                #pragma unroll
                for (int rf = 0; rf < 4; ++rf) {
                    C[rf] = __builtin_amdgcn_mfma_f32_16x16x32_bf16(ahi[rf][kc], bh, C[rf], 0, 0, 0);
                    C[rf] = __builtin_amdgcn_mfma_f32_16x16x32_bf16(alo[rf][kc], bh, C[rf], 0, 0, 0);
                    C[rf] = __builtin_amdgcn_mfma_f32_16x16x32_bf16(ahi[rf][kc], bl, C[rf], 0, 0, 0);
                }
            }
            __builtin_amdgcn_s_setprio(0);

            const int jcol = jb + cg * 16 + l15;
            const float svc = s_lds[t * 32 + cg * 16 + l15];   // broadcast, free
            bool anyband = false;
            float tsum = 0.f;
            #pragma unroll
            for (int rf = 0; rf < 4; ++rf)
                #pragma unroll
                for (int r = 0; r < 4; ++r) {
                    const float ad = fabsf(C[rf][r]);
                    const bool edge = (ad >= DHI);
                    accf[rf][r] += edge ? svc : 0.f;
                    tsum += edge ? si_lds[w * 64 + rf * 16 + l4 * 4 + r] : 0.f;
                    anyband = anyband || (ad >= DLO && ad < DHI);
                }
            // transpose reduce over the 4 l4 lanes sharing this jcol
            tsum += __shfl_xor(tsum, 16);
            tsum += __shfl_xor(tsum, 32);
            if (offdiag && l4 == 0)
                jacc[w][t * 32 + cg * 16 + l15] = tsum;   // each col once/wave

            // ONE wave-uniform branch per cg; rare recompute-and-enqueue
            if (__any(anyband)) {
                #pragma unroll
                for (int rf = 0; rf < 4; ++rf)
                    #pragma unroll
                    for (int r = 0; r < 4; ++r) {
                        const float ad = fabsf(C[rf][r]);
                        if (ad >= DLO && ad < DHI) {
                            int p = atomicAdd(&lqcnt, 1);
                            if (p < LQCAP)
                                lq[p] = symflag |
                                        (((unsigned)(i0 + rf * 16 + l4 * 4 + r)) << 14) |
                                        (unsigned)jcol;
                        }
                    }
            }
        }

        bufc = (bufc == 2) ? 0 : bufc + 1;
        bufs = (bufs == 2) ? 0 : bufs + 1;
    }

    __syncthreads();   // post-loop: full drain OK (once)

    // ---- flush band queue ----
    if (tid == 0) {
        int c = lqcnt; if (c > LQCAP) c = LQCAP;
        lqbase = atomicAdd(gqcnt, c);
        lqcnt = c;
    }
    __syncthreads();
    for (int p = tid; p < lqcnt; p += 256)
        if (lqbase + p < QMAX) gqueue[lqbase + p] = lq[p];

    // ---- forward acc: reduce accf across the 16 l15 lanes, atomicAdd ----
    #pragma unroll
    for (int rf = 0; rf < 4; ++rf)
        #pragma unroll
        for (int r = 0; r < 4; ++r) {
            float v = accf[rf][r];
            v += __shfl_xor(v, 1);
            v += __shfl_xor(v, 2);
            v += __shfl_xor(v, 4);
            v += __shfl_xor(v, 8);
            if (l15 == 0) atomicAdd(&acc[i0 + rf * 16 + l4 * 4 + r], v);
        }

    // ---- transpose acc flush (off-diag only) ----
    if (offdiag) {
        const float v = jacc[0][tid] + jacc[1][tid] + jacc[2][tid] + jacc[3][tid];
        atomicAdd(&acc[jb0 + tid], v);
    }
}

// ---------------------------------------------------------------------------
// Exact f32 re-decision for band pairs: one pair per wave.
// sym flag (bit 31): off-diag pair -> apply both directions.
// ---------------------------------------------------------------------------
__global__ __launch_bounds__(256) void fixup_kernel(const unsigned* __restrict__ q,
                                                    const int* __restrict__ qcnt,
                                                    const float* __restrict__ x,
                                                    const float* __restrict__ s,
                                                    float* __restrict__ acc) {
    int n = *qcnt; if (n > QMAX) n = QMAX;
    const int gw = (blockIdx.x * 256 + threadIdx.x) >> 6;
    const int lane = threadIdx.x & 63;
    const int nw = (gridDim.x * 256) >> 6;
    for (int p = gw; p < n; p += nw) {
        const unsigned e = q[p];
        const int i = (int)((e >> 14) & 16383u), j = (int)(e & 16383u);
        const bool sym = (e >> 31) != 0;
        const float2 av = ((const float2*)(x + (size_t)i * D_FEAT))[lane];
        const float2 bv = ((const float2*)(x + (size_t)j * D_FEAT))[lane];
        float d = fmaf(av.y, bv.y, av.x * bv.x);
        #pragma unroll
        for (int off = 32; off > 0; off >>= 1) d += __shfl_xor(d, off);
        if (lane == 0) {
            const float tt = fmaf(d, d, -THRESH);
            if (tt >= 0.f) {
                atomicAdd(&acc[i], s[j]);
                if (sym) atomicAdd(&acc[j], s[i]);
            }
        }
    }
}

// ---------------------------------------------------------------------------
// out[i][h] = ((acc[i] - s[i])/128) * wsum[h] + b[h]
// ---------------------------------------------------------------------------
__global__ __launch_bounds__(256) void out_kernel(const float* __restrict__ acc,
                                                  const float* __restrict__ s,
                                                  const float* __restrict__ wsum,
                                                  const float* __restrict__ b,
                                                  float* __restrict__ out) {
    int gid = blockIdx.x * blockDim.x + threadIdx.x;
    int i = gid >> 6;
    int h = gid & 63;
    float a = (acc[i] - s[i]) * (1.0f / 128.0f);
    out[gid] = fmaf(a, wsum[h], b[h]);
}

// ---------------------------------------------------------------------------
extern "C" void kernel_launch(void* const* d_in, const int* in_sizes, int n_in,
                              void* d_out, int out_size, void* d_ws, size_t ws_size,
                              hipStream_t stream) {
    const float* x = (const float*)d_in[0];   // [16384,128]
    const float* W = (const float*)d_in[1];   // [64,128]
    const float* b = (const float*)d_in[2];   // [64]
    float* out = (float*)d_out;               // [16384,64]

    float*    s     = (float*)d_ws;                            // 64 KB
    float*    acc   = (float*)((char*)d_ws + 65536);           // 64 KB
    float*    wsum  = (float*)((char*)d_ws + 131072);          // 256 B
    int*      qcnt  = (int*)((char*)d_ws + 131328);
    unsigned* queue = (unsigned*)((char*)d_ws + 262144);       // ~1.8 MB
    unsigned short* xhi = (unsigned short*)((char*)d_ws + (2u << 20));
    unsigned short* xlo = (unsigned short*)((char*)d_ws + (6u << 20));

    convert_rowsum_kernel<<<dim3(2049), dim3(256), 0, stream>>>(x, W, xhi, xlo, s, wsum, acc, qcnt);
    pair_mfma<<<dim3(64, 64), dim3(256), 0, stream>>>(xhi, xlo, s, acc, queue, qcnt);
    fixup_kernel<<<dim3(256), dim3(256), 0, stream>>>(queue, qcnt, x, s, acc);
    out_kernel<<<dim3(N_NODES * HIDDEN / 256), dim3(256), 0, stream>>>(acc, s, wsum, b, out);
}